// Round 1
// baseline (409.270 us; speedup 1.0000x reference)
//
#include <hip/hip_runtime.h>
#include <hip/hip_bf16.h>

// adj[b] = tanh(relu(E_b @ E_b^T)) + 0.5*I
// E_b = concat(spatial[b] (2048x64), temporal[b] (64x64)) -> 2112x64, fp32.
// Output: [16, 2112, 2112] fp32.

#define B_BATCH   16
#define N_SPATIAL 2048
#define T_TEMP    64
#define M_NODES   2112     // 33 * 64
#define D_FEAT    64
#define TILE      64
#define LDS_STRIDE (TILE + 4)   // 68: keeps float4 16B alignment, banks ok

__global__ __launch_bounds__(256, 4)
void gram_tanh_kernel(const float* __restrict__ sp,
                      const float* __restrict__ tp,
                      float* __restrict__ out)
{
    const int b  = blockIdx.z;
    const int ti = blockIdx.y;   // row tile index (0..32)
    const int tj = blockIdx.x;   // col tile index (0..32)

    __shared__ __align__(16) float As[D_FEAT][LDS_STRIDE];  // [k][m]
    __shared__ __align__(16) float Bs[D_FEAT][LDS_STRIDE];  // [k][n]

    const int tid = threadIdx.x;
    const int tx  = tid & 15;    // 0..15 -> 4 cols each
    const int ty  = tid >> 4;    // 0..15 -> 4 rows each

    // ---- stage row-tiles ti (As) and tj (Bs), transposed to k-major ----
    {
        const int r  = tid >> 4;        // 0..15
        const int c4 = (tid & 15) * 4;  // 0,4,...,60
        // tile base pointer: tiles 0..31 are spatial, tile 32 is temporal
        const float* srcA = (ti < 32)
            ? (sp + ((size_t)b * N_SPATIAL + (size_t)ti * TILE) * D_FEAT)
            : (tp + (size_t)b * T_TEMP * D_FEAT);
        const float* srcB = (tj < 32)
            ? (sp + ((size_t)b * N_SPATIAL + (size_t)tj * TILE) * D_FEAT)
            : (tp + (size_t)b * T_TEMP * D_FEAT);
        #pragma unroll
        for (int i = 0; i < 4; ++i) {
            const int row = i * 16 + r;   // 0..63
            float4 a  = *(const float4*)(srcA + (size_t)row * D_FEAT + c4);
            float4 bb = *(const float4*)(srcB + (size_t)row * D_FEAT + c4);
            As[c4 + 0][row] = a.x;  As[c4 + 1][row] = a.y;
            As[c4 + 2][row] = a.z;  As[c4 + 3][row] = a.w;
            Bs[c4 + 0][row] = bb.x; Bs[c4 + 1][row] = bb.y;
            Bs[c4 + 2][row] = bb.z; Bs[c4 + 3][row] = bb.w;
        }
    }
    __syncthreads();

    // ---- 4x4 per-thread accumulation over K=64 ----
    float acc[4][4];
    #pragma unroll
    for (int i = 0; i < 4; ++i)
        #pragma unroll
        for (int j = 0; j < 4; ++j) acc[i][j] = 0.f;

    #pragma unroll 16
    for (int k = 0; k < D_FEAT; ++k) {
        float4 a  = *(const float4*)&As[k][ty * 4];
        float4 bb = *(const float4*)&Bs[k][tx * 4];
        const float av[4] = {a.x, a.y, a.z, a.w};
        const float bv[4] = {bb.x, bb.y, bb.z, bb.w};
        #pragma unroll
        for (int i = 0; i < 4; ++i)
            #pragma unroll
            for (int j = 0; j < 4; ++j)
                acc[i][j] = fmaf(av[i], bv[j], acc[i][j]);
    }

    // ---- epilogue: tanh(relu(x)) (+0.5 on diagonal), coalesced float4 stores ----
    const size_t row0 = (size_t)ti * TILE + ty * 4;
    const size_t col0 = (size_t)tj * TILE + tx * 4;
    float* outb = out + (size_t)b * M_NODES * M_NODES;
    const bool diagTile = (ti == tj);

    #pragma unroll
    for (int i = 0; i < 4; ++i) {
        float v[4];
        #pragma unroll
        for (int j = 0; j < 4; ++j) {
            float x = fmaxf(acc[i][j], 0.f);
            // tanh(x) for x>=0: 1 - 2/(e^{2x}+1); e=inf -> 1 (correct saturation)
            float e = __expf(2.f * x);
            float t = 1.f - 2.f * __builtin_amdgcn_rcpf(e + 1.f);
            if (diagTile && (ty * 4 + i == tx * 4 + j)) t += 0.5f;
            v[j] = t;
        }
        float4 v4 = make_float4(v[0], v[1], v[2], v[3]);
        *(float4*)(outb + (row0 + i) * M_NODES + col0) = v4;
    }
}

extern "C" void kernel_launch(void* const* d_in, const int* in_sizes, int n_in,
                              void* d_out, int out_size, void* d_ws, size_t ws_size,
                              hipStream_t stream) {
    const float* sp = (const float*)d_in[0];   // [16, 2048, 64] fp32
    const float* tp = (const float*)d_in[1];   // [16, 64, 64]   fp32
    float* out = (float*)d_out;                // [16, 2112, 2112] fp32

    dim3 grid(M_NODES / TILE, M_NODES / TILE, B_BATCH);  // 33 x 33 x 16
    dim3 block(256);
    hipLaunchKernelGGL(gram_tanh_kernel, grid, block, 0, stream, sp, tp, out);
}

// Round 2
// 324.127 us; speedup vs baseline: 1.2627x; 1.2627x over previous
//
#include <hip/hip_runtime.h>
#include <hip/hip_fp16.h>

// adj[b] = tanh(relu(E_b @ E_b^T)) + 0.5*I
// E_b = concat(spatial[b] (2048x64), temporal[b] (64x64)) fp32 -> fp16 MFMA,
// fp32 accumulate. Output: [16, 2112, 2112] fp32. Write-bound target.

#define B_BATCH   16
#define N_SPATIAL 2048
#define T_TEMP    64
#define M_NODES   2112     // 33 * 64
#define D_FEAT    64
#define TILE      64
#define LDSK      72       // fp16 row stride: +8 pad -> bank-spread for b128 reads

typedef _Float16 f16x8 __attribute__((ext_vector_type(8)));
typedef float    f32x4 __attribute__((ext_vector_type(4)));

__global__ __launch_bounds__(256, 4)
void gram_tanh_mfma(const float* __restrict__ sp,
                    const float* __restrict__ tp,
                    float* __restrict__ out)
{
    const int b  = blockIdx.z;
    const int ti = blockIdx.y;   // row tile (0..32)
    const int tj = blockIdx.x;   // col tile (0..32)

    __shared__ __align__(16) _Float16 As[TILE][LDSK];
    __shared__ __align__(16) _Float16 Bs[TILE][LDSK];

    const int tid = threadIdx.x;

    // ---- stage + convert fp32 -> fp16 ----
    // thread -> row = tid>>2 (0..63), k-base = (tid&3)*16 : 16 contiguous floats
    {
        const int row = tid >> 2;
        const int kb  = (tid & 3) * 16;
        const float* srcA = (ti < 32)
            ? sp + ((size_t)b * N_SPATIAL + (size_t)ti * TILE) * D_FEAT
            : tp + (size_t)b * T_TEMP * D_FEAT;
        const float* srcB = (tj < 32)
            ? sp + ((size_t)b * N_SPATIAL + (size_t)tj * TILE) * D_FEAT
            : tp + (size_t)b * T_TEMP * D_FEAT;
        const float4* pa = (const float4*)(srcA + (size_t)row * D_FEAT + kb);
        const float4* pb = (const float4*)(srcB + (size_t)row * D_FEAT + kb);

        f16x8 ha0, ha1, hb0, hb1;
        #pragma unroll
        for (int u = 0; u < 2; ++u) {
            float4 a = pa[u];
            ha0[u*4+0] = (_Float16)a.x; ha0[u*4+1] = (_Float16)a.y;
            ha0[u*4+2] = (_Float16)a.z; ha0[u*4+3] = (_Float16)a.w;
            float4 bb = pb[u];
            hb0[u*4+0] = (_Float16)bb.x; hb0[u*4+1] = (_Float16)bb.y;
            hb0[u*4+2] = (_Float16)bb.z; hb0[u*4+3] = (_Float16)bb.w;
        }
        #pragma unroll
        for (int u = 0; u < 2; ++u) {
            float4 a = pa[2+u];
            ha1[u*4+0] = (_Float16)a.x; ha1[u*4+1] = (_Float16)a.y;
            ha1[u*4+2] = (_Float16)a.z; ha1[u*4+3] = (_Float16)a.w;
            float4 bb = pb[2+u];
            hb1[u*4+0] = (_Float16)bb.x; hb1[u*4+1] = (_Float16)bb.y;
            hb1[u*4+2] = (_Float16)bb.z; hb1[u*4+3] = (_Float16)bb.w;
        }
        *(f16x8*)&As[row][kb]     = ha0;   // 16B-aligned: row*144 + kb*2
        *(f16x8*)&As[row][kb + 8] = ha1;
        *(f16x8*)&Bs[row][kb]     = hb0;
        *(f16x8*)&Bs[row][kb + 8] = hb1;
    }
    __syncthreads();

    // ---- MFMA: wave w computes rows [16w, 16w+16) x all 64 cols ----
    const int wave = tid >> 6;
    const int lane = tid & 63;
    const int lr   = lane & 15;   // m (A) / n (B) index within 16-tile
    const int q    = lane >> 4;   // quad -> k-slice / output row group

    f32x4 acc[4];
    #pragma unroll
    for (int t = 0; t < 4; ++t) acc[t] = (f32x4){0.f, 0.f, 0.f, 0.f};

    #pragma unroll
    for (int s = 0; s < 2; ++s) {                 // K = 64 = 2 x 32
        f16x8 afrag = *(const f16x8*)&As[wave * 16 + lr][s * 32 + q * 8];
        #pragma unroll
        for (int t = 0; t < 4; ++t) {             // 4 col-tiles of 16
            f16x8 bfrag = *(const f16x8*)&Bs[t * 16 + lr][s * 32 + q * 8];
            acc[t] = __builtin_amdgcn_mfma_f32_16x16x32_f16(afrag, bfrag, acc[t], 0, 0, 0);
        }
    }

    // ---- epilogue: tanh(relu(x)) (+0.5 diag), dword stores (4x64B segs/wave) ----
    float* outb = out + (size_t)b * M_NODES * M_NODES;
    const bool diagTile = (ti == tj);
    const int rbase = wave * 16 + q * 4;          // row within 64-tile

    #pragma unroll
    for (int t = 0; t < 4; ++t) {
        const int cin = t * 16 + lr;              // col within 64-tile
        #pragma unroll
        for (int i = 0; i < 4; ++i) {
            float x = fmaxf(acc[t][i], 0.f);
            // tanh(x), x>=0: 1 - 2/(e^{2x}+1); exp->inf saturates to 1 correctly
            float e = __expf(2.f * x);
            float v = 1.f - 2.f * __builtin_amdgcn_rcpf(e + 1.f);
            if (diagTile && (rbase + i == cin)) v += 0.5f;
            outb[(size_t)(ti * TILE + rbase + i) * M_NODES + (tj * TILE + cin)] = v;
        }
    }
}

extern "C" void kernel_launch(void* const* d_in, const int* in_sizes, int n_in,
                              void* d_out, int out_size, void* d_ws, size_t ws_size,
                              hipStream_t stream) {
    const float* sp = (const float*)d_in[0];   // [16, 2048, 64] fp32
    const float* tp = (const float*)d_in[1];   // [16, 64, 64]   fp32
    float* out = (float*)d_out;                // [16, 2112, 2112] fp32

    dim3 grid(M_NODES / TILE, M_NODES / TILE, B_BATCH);  // 33 x 33 x 16
    dim3 block(256);
    hipLaunchKernelGGL(gram_tanh_mfma, grid, block, 0, stream, sp, tp, out);
}

// Round 3
// 313.332 us; speedup vs baseline: 1.3062x; 1.0345x over previous
//
#include <hip/hip_runtime.h>
#include <hip/hip_fp16.h>

// adj[b] = tanh(relu(E_b @ E_b^T)) + 0.5*I
// E_b = concat(spatial[b] (2048x64), temporal[b] (64x64)) fp32 -> fp16 MFMA,
// fp32 accumulate. Output: [16, 2112, 2112] fp32.
// R3: LDS-transposed epilogue -> global_store_dwordx4 (write-BW bound target).

#define B_BATCH   16
#define N_SPATIAL 2048
#define T_TEMP    64
#define M_NODES   2112     // 33 * 64
#define D_FEAT    64
#define TILE      64
#define LDSK      72       // fp16 k-stride (+8 pad)
#define CSTR      68       // fp32 epilogue tile stride (+4 pad, 2-way banks = free)

typedef _Float16 f16x8 __attribute__((ext_vector_type(8)));
typedef float    f32x4 __attribute__((ext_vector_type(4)));

__global__ __launch_bounds__(256, 6)
void gram_tanh_mfma(const float* __restrict__ sp,
                    const float* __restrict__ tp,
                    float* __restrict__ out)
{
    const int b  = blockIdx.z;
    const int ti = blockIdx.y;   // row tile (0..32)
    const int tj = blockIdx.x;   // col tile (0..32)

    // Alias: As/Bs (fp16 staging, 18432 B) then Ct (fp32 epilogue tile, 17408 B)
    __shared__ __align__(16) unsigned char smem[2 * TILE * LDSK * 2];
    _Float16 (*As)[LDSK] = reinterpret_cast<_Float16(*)[LDSK]>(smem);
    _Float16 (*Bs)[LDSK] = reinterpret_cast<_Float16(*)[LDSK]>(smem + TILE * LDSK * 2);
    float    (*Ct)[CSTR] = reinterpret_cast<float(*)[CSTR]>(smem);

    const int tid = threadIdx.x;

    // ---- stage + convert fp32 -> fp16: row = tid>>2, 16 consecutive k ----
    {
        const int row = tid >> 2;
        const int kb  = (tid & 3) * 16;
        const float* srcA = (ti < 32)
            ? sp + ((size_t)b * N_SPATIAL + (size_t)ti * TILE) * D_FEAT
            : tp + (size_t)b * T_TEMP * D_FEAT;
        const float* srcB = (tj < 32)
            ? sp + ((size_t)b * N_SPATIAL + (size_t)tj * TILE) * D_FEAT
            : tp + (size_t)b * T_TEMP * D_FEAT;
        const float4* pa = (const float4*)(srcA + (size_t)row * D_FEAT + kb);
        const float4* pb = (const float4*)(srcB + (size_t)row * D_FEAT + kb);

        f16x8 ha0, ha1, hb0, hb1;
        #pragma unroll
        for (int u = 0; u < 2; ++u) {
            float4 a = pa[u];
            ha0[u*4+0] = (_Float16)a.x; ha0[u*4+1] = (_Float16)a.y;
            ha0[u*4+2] = (_Float16)a.z; ha0[u*4+3] = (_Float16)a.w;
            float4 bb = pb[u];
            hb0[u*4+0] = (_Float16)bb.x; hb0[u*4+1] = (_Float16)bb.y;
            hb0[u*4+2] = (_Float16)bb.z; hb0[u*4+3] = (_Float16)bb.w;
        }
        #pragma unroll
        for (int u = 0; u < 2; ++u) {
            float4 a = pa[2+u];
            ha1[u*4+0] = (_Float16)a.x; ha1[u*4+1] = (_Float16)a.y;
            ha1[u*4+2] = (_Float16)a.z; ha1[u*4+3] = (_Float16)a.w;
            float4 bb = pb[2+u];
            hb1[u*4+0] = (_Float16)bb.x; hb1[u*4+1] = (_Float16)bb.y;
            hb1[u*4+2] = (_Float16)bb.z; hb1[u*4+3] = (_Float16)bb.w;
        }
        *(f16x8*)&As[row][kb]     = ha0;
        *(f16x8*)&As[row][kb + 8] = ha1;
        *(f16x8*)&Bs[row][kb]     = hb0;
        *(f16x8*)&Bs[row][kb + 8] = hb1;
    }
    __syncthreads();

    // ---- MFMA: wave w -> rows [16w,16w+16) x all 64 cols ----
    const int wave = tid >> 6;
    const int lane = tid & 63;
    const int lr   = lane & 15;   // m (A) / n (B) within 16-tile
    const int q    = lane >> 4;   // quad -> k-slice / C row group

    f32x4 acc[4];
    #pragma unroll
    for (int t = 0; t < 4; ++t) acc[t] = (f32x4){0.f, 0.f, 0.f, 0.f};

    #pragma unroll
    for (int s = 0; s < 2; ++s) {                 // K = 64 = 2 x 32
        f16x8 afrag = *(const f16x8*)&As[wave * 16 + lr][s * 32 + q * 8];
        #pragma unroll
        for (int t = 0; t < 4; ++t) {
            f16x8 bfrag = *(const f16x8*)&Bs[t * 16 + lr][s * 32 + q * 8];
            acc[t] = __builtin_amdgcn_mfma_f32_16x16x32_f16(afrag, bfrag, acc[t], 0, 0, 0);
        }
    }
    __syncthreads();   // As/Bs dead; Ct aliases them

    // ---- tanh(relu) + diag in C-layout, park in LDS ----
    const bool diagTile = (ti == tj);
    #pragma unroll
    for (int t = 0; t < 4; ++t) {
        const int col = t * 16 + lr;
        #pragma unroll
        for (int i = 0; i < 4; ++i) {
            const int row = wave * 16 + q * 4 + i;
            float x = fmaxf(acc[t][i], 0.f);
            // tanh(x), x>=0: 1 - 2/(e^{2x}+1); exp->inf saturates to 1 correctly
            float e = __expf(2.f * x);
            float v = 1.f - 2.f * __builtin_amdgcn_rcpf(e + 1.f);
            if (diagTile && (row == col)) v += 0.5f;
            Ct[row][col] = v;
        }
    }
    __syncthreads();

    // ---- wide coalesced stores: 4x dwordx4 per thread ----
    {
        const int row = tid >> 2;          // 0..63
        float* dst = out + (size_t)b * M_NODES * M_NODES
                         + (size_t)(ti * TILE + row) * M_NODES + tj * TILE;
        #pragma unroll
        for (int u = 0; u < 4; ++u) {
            const int c4 = (tid & 3) * 4 + 16 * u;   // float offset 0..60
            *(float4*)(dst + c4) = *(const float4*)&Ct[row][c4];
        }
    }
}

extern "C" void kernel_launch(void* const* d_in, const int* in_sizes, int n_in,
                              void* d_out, int out_size, void* d_ws, size_t ws_size,
                              hipStream_t stream) {
    const float* sp = (const float*)d_in[0];   // [16, 2048, 64] fp32
    const float* tp = (const float*)d_in[1];   // [16, 64, 64]   fp32
    float* out = (float*)d_out;                // [16, 2112, 2112] fp32

    dim3 grid(M_NODES / TILE, M_NODES / TILE, B_BATCH);  // 33 x 33 x 16
    dim3 block(256);
    hipLaunchKernelGGL(gram_tanh_mfma, grid, block, 0, stream, sp, tp, out);
}

// Round 5
// 281.298 us; speedup vs baseline: 1.4549x; 1.1139x over previous
//
#include <hip/hip_runtime.h>
#include <hip/hip_fp16.h>

// adj[b] = tanh(relu(E_b @ E_b^T)) + 0.5*I
// E_b = concat(spatial[b] (2048x64), temporal[b] (64x64)) fp32 -> fp16 MFMA,
// fp32 accumulate. Output: [16, 2112, 2112] fp32.
// R5: R4's XCD-partitioned swizzle KEPT; LDS aliasing REMOVED (Ct gets its own
// storage) — the aliased Ct-over-As/Bs reuse is the prime suspect for R4's
// scheduling-sensitive post-timing divergence.

#define B_BATCH   16
#define N_SPATIAL 2048
#define T_TEMP    64
#define M_NODES   2112     // 33 * 64
#define D_FEAT    64
#define TILE      64
#define LDSK      72       // fp16 k-stride (+8 pad)
#define CSTR      68       // fp32 epilogue tile stride (+4 pad, 2-way banks = free)

#define TILES_PER_BATCH 1089   // 33*33
#define TOTAL_TILES     17424  // 1089*16 = 8 * 2178
#define TILES_PER_XCD   2178

typedef _Float16 f16x8 __attribute__((ext_vector_type(8)));
typedef float    f32x4 __attribute__((ext_vector_type(4)));

__global__ __launch_bounds__(256, 4)
void gram_tanh_mfma(const float* __restrict__ sp,
                    const float* __restrict__ tp,
                    float* __restrict__ out)
{
    // ---- XCD-aware decode: wg lin -> XCD (lin&7, round-robin dispatch);
    // XCD k owns contiguous tile ids [2178k, 2178(k+1)) = batches 2k,2k+1,
    // so each XCD streams sequentially through a private 71 MB output region.
    const int lin = blockIdx.x;
    const int t   = (lin & 7) * TILES_PER_XCD + (lin >> 3);
    const int b   = t / TILES_PER_BATCH;
    const int r   = t - b * TILES_PER_BATCH;
    const int ti  = r / 33;        // row tile (0..32)
    const int tj  = r - ti * 33;   // col tile (0..32), fastest -> sequential writes

    __shared__ __align__(16) _Float16 As[TILE][LDSK];   // 9216 B
    __shared__ __align__(16) _Float16 Bs[TILE][LDSK];   // 9216 B
    __shared__ __align__(16) float    Ct[TILE][CSTR];   // 17408 B (no aliasing)

    const int tid = threadIdx.x;

    // ---- stage + convert fp32 -> fp16: row = tid>>2, 16 consecutive k ----
    {
        const int row = tid >> 2;
        const int kb  = (tid & 3) * 16;
        const float* srcA = (ti < 32)
            ? sp + ((size_t)b * N_SPATIAL + (size_t)ti * TILE) * D_FEAT
            : tp + (size_t)b * T_TEMP * D_FEAT;
        const float* srcB = (tj < 32)
            ? sp + ((size_t)b * N_SPATIAL + (size_t)tj * TILE) * D_FEAT
            : tp + (size_t)b * T_TEMP * D_FEAT;
        const float4* pa = (const float4*)(srcA + (size_t)row * D_FEAT + kb);
        const float4* pb = (const float4*)(srcB + (size_t)row * D_FEAT + kb);

        f16x8 ha0, ha1, hb0, hb1;
        #pragma unroll
        for (int u = 0; u < 2; ++u) {
            float4 a = pa[u];
            ha0[u*4+0] = (_Float16)a.x; ha0[u*4+1] = (_Float16)a.y;
            ha0[u*4+2] = (_Float16)a.z; ha0[u*4+3] = (_Float16)a.w;
            float4 bb = pb[u];
            hb0[u*4+0] = (_Float16)bb.x; hb0[u*4+1] = (_Float16)bb.y;
            hb0[u*4+2] = (_Float16)bb.z; hb0[u*4+3] = (_Float16)bb.w;
        }
        #pragma unroll
        for (int u = 0; u < 2; ++u) {
            float4 a = pa[2+u];
            ha1[u*4+0] = (_Float16)a.x; ha1[u*4+1] = (_Float16)a.y;
            ha1[u*4+2] = (_Float16)a.z; ha1[u*4+3] = (_Float16)a.w;
            float4 bb = pb[2+u];
            hb1[u*4+0] = (_Float16)bb.x; hb1[u*4+1] = (_Float16)bb.y;
            hb1[u*4+2] = (_Float16)bb.z; hb1[u*4+3] = (_Float16)bb.w;
        }
        *(f16x8*)&As[row][kb]     = ha0;
        *(f16x8*)&As[row][kb + 8] = ha1;
        *(f16x8*)&Bs[row][kb]     = hb0;
        *(f16x8*)&Bs[row][kb + 8] = hb1;
    }
    __syncthreads();

    // ---- MFMA: wave w -> rows [16w,16w+16) x all 64 cols ----
    const int wave = tid >> 6;
    const int lane = tid & 63;
    const int lr   = lane & 15;   // m (A) / n (B) within 16-tile
    const int q    = lane >> 4;   // quad -> k-slice / C row group

    f32x4 acc[4];
    #pragma unroll
    for (int tt = 0; tt < 4; ++tt) acc[tt] = (f32x4){0.f, 0.f, 0.f, 0.f};

    #pragma unroll
    for (int s = 0; s < 2; ++s) {                 // K = 64 = 2 x 32
        f16x8 afrag = *(const f16x8*)&As[wave * 16 + lr][s * 32 + q * 8];
        #pragma unroll
        for (int tt = 0; tt < 4; ++tt) {
            f16x8 bfrag = *(const f16x8*)&Bs[tt * 16 + lr][s * 32 + q * 8];
            acc[tt] = __builtin_amdgcn_mfma_f32_16x16x32_f16(afrag, bfrag, acc[tt], 0, 0, 0);
        }
    }

    // ---- tanh(relu) + diag in C-layout, park in LDS (separate buffer, no
    // barrier needed before writes: Ct is disjoint from As/Bs) ----
    const bool diagTile = (ti == tj);
    #pragma unroll
    for (int tt = 0; tt < 4; ++tt) {
        const int col = tt * 16 + lr;
        #pragma unroll
        for (int i = 0; i < 4; ++i) {
            const int row = wave * 16 + q * 4 + i;
            float x = fmaxf(acc[tt][i], 0.f);
            // tanh(x), x>=0: 1 - 2/(e^{2x}+1); exp->inf saturates to 1 correctly
            float e = __expf(2.f * x);
            float v = 1.f - 2.f * __builtin_amdgcn_rcpf(e + 1.f);
            if (diagTile && (row == col)) v += 0.5f;
            Ct[row][col] = v;
        }
    }
    __syncthreads();

    // ---- wide coalesced stores: 4x dwordx4 per thread ----
    {
        const int row = tid >> 2;          // 0..63
        float* dst = out + (size_t)b * M_NODES * M_NODES
                         + (size_t)(ti * TILE + row) * M_NODES + tj * TILE;
        #pragma unroll
        for (int u = 0; u < 4; ++u) {
            const int c4 = (tid & 3) * 4 + 16 * u;   // float offset 0..60
            *(float4*)(dst + c4) = *(const float4*)&Ct[row][c4];
        }
    }
}

extern "C" void kernel_launch(void* const* d_in, const int* in_sizes, int n_in,
                              void* d_out, int out_size, void* d_ws, size_t ws_size,
                              hipStream_t stream) {
    const float* sp = (const float*)d_in[0];   // [16, 2048, 64] fp32
    const float* tp = (const float*)d_in[1];   // [16, 64, 64]   fp32
    float* out = (float*)d_out;                // [16, 2112, 2112] fp32

    dim3 grid(TOTAL_TILES);                    // 1D; kernel does XCD-aware decode
    dim3 block(256);
    hipLaunchKernelGGL(gram_tanh_mfma, grid, block, 0, stream, sp, tp, out);
}

// Round 6
// 279.501 us; speedup vs baseline: 1.4643x; 1.0064x over previous
//
#include <hip/hip_runtime.h>
#include <hip/hip_fp16.h>

// adj[b] = tanh(relu(E_b @ E_b^T)) + 0.5*I
// E_b = concat(spatial[b] (2048x64), temporal[b] (64x64)) fp32 -> fp16 MFMA,
// fp32 accumulate. Output: [16, 2112, 2112] fp32.
// R6: 64x128 per WG (two tj sub-tiles, one staging barrier per 32 KB written),
// wave-private epilogue transpose (no second __syncthreads). XCD-partitioned
// tile order kept from R5 (validated win: each XCD streams a private region).

#define B_BATCH   16
#define N_SPATIAL 2048
#define T_TEMP    64
#define M_NODES   2112     // 33 * 64
#define D_FEAT    64
#define TILE      64
#define LDSK      72       // fp16 k-stride (+8 pad)
#define CSTR      68       // fp32 epilogue tile stride (+4 pad)

// per batch: 33 ti strips x 17 tj-groups (16 groups of 2 tiles + 1 of 1)
#define GROUPS_PER_STRIP 17
#define WGS_PER_BATCH    (33 * GROUPS_PER_STRIP)   // 561
#define TOTAL_WGS        (WGS_PER_BATCH * B_BATCH) // 8976 = 8 * 1122
#define WGS_PER_XCD      (TOTAL_WGS / 8)           // 1122 = 2 batches

typedef _Float16 f16x8 __attribute__((ext_vector_type(8)));
typedef float    f32x4 __attribute__((ext_vector_type(4)));

__device__ __forceinline__ f16x8 cvt2(const float4* p) {
    float4 a = p[0], c = p[1];
    f16x8 h;
    h[0] = (_Float16)a.x; h[1] = (_Float16)a.y;
    h[2] = (_Float16)a.z; h[3] = (_Float16)a.w;
    h[4] = (_Float16)c.x; h[5] = (_Float16)c.y;
    h[6] = (_Float16)c.z; h[7] = (_Float16)c.w;
    return h;
}

__global__ __launch_bounds__(256, 3)
void gram_tanh_mfma(const float* __restrict__ sp,
                    const float* __restrict__ tp,
                    float* __restrict__ out)
{
    // ---- XCD-aware decode: wg lin -> XCD (lin&7, round-robin dispatch);
    // XCD k owns local ids [0,1122) = batches 2k,2k+1, tj fastest.
    const int lin = blockIdx.x;
    const int xcd = lin & 7;
    const int l   = lin >> 3;            // 0..1121
    const int bo  = l / WGS_PER_BATCH;   // 0,1
    const int rr  = l - bo * WGS_PER_BATCH;
    const int ti  = rr / GROUPS_PER_STRIP;          // 0..32
    const int g   = rr - ti * GROUPS_PER_STRIP;     // 0..16
    const int b   = 2 * xcd + bo;
    const int tj0 = 2 * g;
    const bool have2 = (tj0 + 1 < 33);
    const int tj1 = have2 ? tj0 + 1 : 32;           // clamp (g==16 -> dup of tj0)

    __shared__ __align__(16) _Float16 As[TILE][LDSK];       //  9216 B
    __shared__ __align__(16) _Float16 Bs[2][TILE][LDSK];    // 18432 B
    __shared__ __align__(16) float    Ct[TILE][CSTR];       // 17408 B  -> 45056 B

    const int tid = threadIdx.x;

    // ---- stage + convert fp32 -> fp16: row = tid>>2, 16 consecutive k ----
    {
        const int row = tid >> 2;
        const int kb  = (tid & 3) * 16;
        const float* srcA = (ti < 32)
            ? sp + ((size_t)b * N_SPATIAL + (size_t)ti * TILE) * D_FEAT
            : tp + (size_t)b * T_TEMP * D_FEAT;
        const float* srcB0 = (tj0 < 32)
            ? sp + ((size_t)b * N_SPATIAL + (size_t)tj0 * TILE) * D_FEAT
            : tp + (size_t)b * T_TEMP * D_FEAT;
        const float* srcB1 = (tj1 < 32)
            ? sp + ((size_t)b * N_SPATIAL + (size_t)tj1 * TILE) * D_FEAT
            : tp + (size_t)b * T_TEMP * D_FEAT;
        const float4* pa  = (const float4*)(srcA  + (size_t)row * D_FEAT + kb);
        const float4* pb0 = (const float4*)(srcB0 + (size_t)row * D_FEAT + kb);
        const float4* pb1 = (const float4*)(srcB1 + (size_t)row * D_FEAT + kb);

        *(f16x8*)&As[row][kb]        = cvt2(pa);
        *(f16x8*)&As[row][kb + 8]    = cvt2(pa + 2);
        *(f16x8*)&Bs[0][row][kb]     = cvt2(pb0);
        *(f16x8*)&Bs[0][row][kb + 8] = cvt2(pb0 + 2);
        *(f16x8*)&Bs[1][row][kb]     = cvt2(pb1);
        *(f16x8*)&Bs[1][row][kb + 8] = cvt2(pb1 + 2);
    }
    __syncthreads();   // the ONLY barrier

    // ---- MFMA: wave w -> rows [16w,16w+16) x 2 sub-tiles of 64 cols ----
    const int wave = tid >> 6;
    const int lane = tid & 63;
    const int lr   = lane & 15;   // m (A) / n (B) within 16-tile
    const int q    = lane >> 4;   // quad -> k-slice / C row group

    f32x4 acc[2][4];
    #pragma unroll
    for (int n = 0; n < 2; ++n)
        #pragma unroll
        for (int tt = 0; tt < 4; ++tt) acc[n][tt] = (f32x4){0.f, 0.f, 0.f, 0.f};

    #pragma unroll
    for (int s = 0; s < 2; ++s) {                 // K = 64 = 2 x 32
        f16x8 afrag = *(const f16x8*)&As[wave * 16 + lr][s * 32 + q * 8];
        #pragma unroll
        for (int n = 0; n < 2; ++n) {
            #pragma unroll
            for (int tt = 0; tt < 4; ++tt) {
                f16x8 bfrag = *(const f16x8*)&Bs[n][tt * 16 + lr][s * 32 + q * 8];
                acc[n][tt] = __builtin_amdgcn_mfma_f32_16x16x32_f16(afrag, bfrag, acc[n][tt], 0, 0, 0);
            }
        }
    }

    // ---- per sub-tile: tanh(relu)+diag -> wave-private Ct slice -> stores ----
    // Wave w only touches Ct rows [16w,16w+16): no cross-wave sync needed.
    #pragma unroll
    for (int n = 0; n < 2; ++n) {
        if (n == 1 && !have2) break;              // wave-uniform skip (dup tile)
        const int tjn = n ? tj1 : tj0;
        const bool diagT = (ti == tjn);
        #pragma unroll
        for (int tt = 0; tt < 4; ++tt) {
            const int col = tt * 16 + lr;
            #pragma unroll
            for (int i = 0; i < 4; ++i) {
                const int row = wave * 16 + q * 4 + i;
                float x = fmaxf(acc[n][tt][i], 0.f);
                // tanh(x), x>=0: 1 - 2/(e^{2x}+1); exp->inf saturates to 1
                float e = __expf(2.f * x);
                float v = 1.f - 2.f * __builtin_amdgcn_rcpf(e + 1.f);
                if (diagT && (row == col)) v += 0.5f;
                Ct[row][col] = v;
            }
        }
        // in-wave LDS WAR/RAW ordering via lgkmcnt; no __syncthreads
        const int rs = lane >> 2;                 // 0..15 row within wave slice
        float* dst = out + (size_t)b * M_NODES * M_NODES
                         + (size_t)(ti * TILE + wave * 16 + rs) * M_NODES
                         + tjn * TILE;
        #pragma unroll
        for (int u = 0; u < 4; ++u) {
            const int c4 = (lane & 3) * 4 + 16 * u;   // float offset 0..60
            *(float4*)(dst + c4) = *(const float4*)&Ct[wave * 16 + rs][c4];
        }
    }
}

extern "C" void kernel_launch(void* const* d_in, const int* in_sizes, int n_in,
                              void* d_out, int out_size, void* d_ws, size_t ws_size,
                              hipStream_t stream) {
    const float* sp = (const float*)d_in[0];   // [16, 2048, 64] fp32
    const float* tp = (const float*)d_in[1];   // [16, 64, 64]   fp32
    float* out = (float*)d_out;                // [16, 2112, 2112] fp32

    dim3 grid(TOTAL_WGS);                      // 8976; kernel does XCD decode
    dim3 block(256);
    hipLaunchKernelGGL(gram_tanh_mfma, grid, block, 0, stream, sp, tp, out);
}